// Round 1
// baseline (587.645 us; speedup 1.0000x reference)
//
#include <hip/hip_runtime.h>

typedef unsigned short ushort_t;
typedef unsigned int uint_t;
typedef __attribute__((ext_vector_type(8))) short bhalf8;   // 8 bf16 (4 VGPRs)
typedef __attribute__((ext_vector_type(4))) float f32x4;
typedef __attribute__((ext_vector_type(4))) uint_t u32x4;

#define C_LIN  0.04419417382415922f     // 1/sqrt(512)
#define C_CONV 0.014731391274719738f    // 1/sqrt(512*9)

__device__ __forceinline__ ushort_t f2bf(float f) {
    uint_t u = __float_as_uint(f);
    u += 0x7fffu + ((u >> 16) & 1u);    // round-to-nearest-even
    return (ushort_t)(u >> 16);
}

// ---------------- kernel 1: mapping network + style (all f32, exact) --------
__global__ void style_k(const float* __restrict__ s,
                        const float* __restrict__ w0, const float* __restrict__ b0, const float* __restrict__ a0,
                        const float* __restrict__ w1, const float* __restrict__ b1, const float* __restrict__ a1,
                        const float* __restrict__ sw, const float* __restrict__ sb,
                        float* __restrict__ style_c) {
    __shared__ float z[512];
    const int b = blockIdx.x, j = threadIdx.x;
    z[j] = s[b * 512 + j];
    __syncthreads();

    float acc = 0.f;
    {   const float4* wr = (const float4*)(w0 + (size_t)j * 512);
        for (int i = 0; i < 128; ++i) {
            float4 w = wr[i];
            acc += w.x * z[4*i] + w.y * z[4*i+1] + w.z * z[4*i+2] + w.w * z[4*i+3];
        } }
    acc = acc * C_LIN + b0[j];
    float zv = acc >= 0.f ? acc : a0[j] * acc;
    __syncthreads(); z[j] = zv; __syncthreads();

    acc = 0.f;
    {   const float4* wr = (const float4*)(w1 + (size_t)j * 512);
        for (int i = 0; i < 128; ++i) {
            float4 w = wr[i];
            acc += w.x * z[4*i] + w.y * z[4*i+1] + w.z * z[4*i+2] + w.w * z[4*i+3];
        } }
    acc = acc * C_LIN + b1[j];
    zv = acc >= 0.f ? acc : a1[j] * acc;
    __syncthreads(); z[j] = zv; __syncthreads();

    acc = 0.f;
    {   const float4* wr = (const float4*)(sw + (size_t)j * 512);
        for (int i = 0; i < 128; ++i) {
            float4 w = wr[i];
            acc += w.x * z[4*i] + w.y * z[4*i+1] + w.z * z[4*i+2] + w.w * z[4*i+3];
        } }
    acc = acc * C_LIN + sb[j];
    style_c[b * 512 + j] = acc * C_CONV;        // fold c_conv into style
}

// ---------------- kernel 2: wsq[cout][cin] = sum_tap conv_w^2 ---------------
__global__ void wsq_k(const float* __restrict__ cw, float* __restrict__ wsq) {
    int idx = blockIdx.x * 256 + threadIdx.x;   // < 262144
    const float* p = cw + (size_t)idx * 9;
    float sum = 0.f;
#pragma unroll
    for (int k = 0; k < 9; ++k) { float v = p[k]; sum += v * v; }
    wsq[idx] = sum;
}

// ---------------- kernel 3: sigma_inv[b][cout] ------------------------------
__global__ void sigma_k(const float* __restrict__ style_c, const float* __restrict__ wsq,
                        float* __restrict__ sig) {
    __shared__ float s2[512];
    const int b = blockIdx.x, c = threadIdx.x;
    float v = style_c[b * 512 + c];
    s2[c] = v * v;
    __syncthreads();
    const float4* wr = (const float4*)(wsq + (size_t)c * 512);
    float acc = 0.f;
    for (int i = 0; i < 128; ++i) {
        float4 w = wr[i];
        acc += w.x * s2[4*i] + w.y * s2[4*i+1] + w.z * s2[4*i+2] + w.w * s2[4*i+3];
    }
    sig[b * 512 + c] = 1.0f / sqrtf(acc + 1e-8f);
}

// ---------------- kernel 4: conv_w [co][ci][9] -> bf16 [tap][co][ci] --------
__global__ void wbf_k(const float* __restrict__ cw, ushort_t* __restrict__ wbf) {
    int idx = blockIdx.x * 256 + threadIdx.x;   // < 2359296
    int tap = idx >> 18;
    int rem = idx & 262143;
    int cout = rem >> 9, cin = rem & 511;
    wbf[idx] = f2bf(cw[(((size_t)cout * 512) + cin) * 9 + tap]);
}

// ---------------- kernel 5 (optional): x -> bf16 NHWC, style-modulated ------
__global__ void xmod_k(const float* __restrict__ x, const float* __restrict__ style_c,
                       ushort_t* __restrict__ xm) {
    const int y = blockIdx.x, b = blockIdx.y, tid = threadIdx.x;
    const float* xp = x + ((size_t)b * 512) * 4096 + y * 64;            // x[b][ci][y][0]
    ushort_t* op = xm + (((size_t)b * 64 + y) * 64) * 512;              // xm[b][y][x][ci]
    __shared__ ushort_t tile[32][65];
    for (int cin0 = 0; cin0 < 512; cin0 += 32) {
        for (int i = tid; i < 2048; i += 256) {                         // (ci, x) load, coalesced
            int ci = i >> 6, xc = i & 63;
            float v = xp[(size_t)(cin0 + ci) * 4096 + xc] * style_c[b * 512 + cin0 + ci];
            tile[ci][xc] = f2bf(v);
        }
        __syncthreads();
        for (int i = tid; i < 2048; i += 256) {                         // (x, ci) store, ci fastest
            int xc = i >> 5, ci = i & 31;
            op[(size_t)xc * 512 + cin0 + ci] = tile[ci][xc];
        }
        __syncthreads();
    }
}

// ---------------- kernel 6: implicit-GEMM conv via MFMA ---------------------
template <bool XPRE>
__global__ __launch_bounds__(256, 2)
void conv_k(const float* __restrict__ x, const ushort_t* __restrict__ xm,
            const ushort_t* __restrict__ wbf, const float* __restrict__ style_c,
            const float* __restrict__ sig, float* __restrict__ out) {
    __shared__ __align__(16) ushort_t xs[6 * 66 * 40];   // [row6][col66][cin32 pad40]
    __shared__ __align__(16) ushort_t wt[9 * 64 * 40];   // [tap9][cout64][cin32 pad40]

    const int tid  = threadIdx.x;
    const int lane = tid & 63;
    const int wv   = tid >> 6;          // wave 0..3 -> output row r0+wv
    const int l15  = lane & 15, l4 = lane >> 4;
    const int r0    = blockIdx.x * 4;
    const int cout0 = blockIdx.y * 64;
    const int b     = blockIdx.z;

    f32x4 acc[4][4] = {};

    for (int c0 = 0; c0 < 512; c0 += 32) {
        __syncthreads();   // previous iteration's readers done before overwrite
        // ---- stage W tile: 9 taps x 64 couts x 4 groups of 8 cins
        for (int i = tid; i < 9 * 64 * 4; i += 256) {
            int g = i & 3, cout = (i >> 2) & 63, tap = i >> 8;
            u32x4 v = *(const u32x4*)(wbf + (((size_t)tap * 512 + cout0 + cout) * 512 + c0 + g * 8));
            *(u32x4*)(wt + (tap * 64 + cout) * 40 + g * 8) = v;
        }
        // ---- stage X tile: 6 rows x 66 cols x 4 groups (edge-replicated)
        if (XPRE) {
            for (int i = tid; i < 6 * 66 * 4; i += 256) {
                int g = i & 3, cg = i >> 2;
                int col = cg % 66, row = cg / 66;
                int gy = min(max(r0 - 1 + row, 0), 63);
                int gx = min(max(col - 1, 0), 63);
                u32x4 v = *(const u32x4*)(xm + ((((size_t)b * 64 + gy) * 64 + gx) * 512 + c0 + g * 8));
                *(u32x4*)(xs + (row * 66 + col) * 40 + g * 8) = v;
            }
        } else {
            for (int i = tid; i < 6 * 66 * 4; i += 256) {
                int col = i % 66, t = i / 66;
                int g = t & 3, row = t >> 2;
                int gy = min(max(r0 - 1 + row, 0), 63);
                int gx = min(max(col - 1, 0), 63);
                const float* xp = x + (((size_t)b * 512 + c0 + g * 8) * 64 + gy) * 64 + gx;
                ushort_t tmp[8];
#pragma unroll
                for (int k = 0; k < 8; ++k)
                    tmp[k] = f2bf(xp[(size_t)k * 4096] * style_c[b * 512 + c0 + g * 8 + k]);
                *(u32x4*)(xs + (row * 66 + col) * 40 + g * 8) = *(const u32x4*)tmp;
            }
        }
        __syncthreads();
        // ---- MFMA: 9 taps x 4x4 fragments, K=32
#pragma unroll
        for (int dy = 0; dy < 3; ++dy) {
#pragma unroll
            for (int dx = 0; dx < 3; ++dx) {
                const int tap = dy * 3 + dx;
                bhalf8 af[4], bf[4];
#pragma unroll
                for (int m = 0; m < 4; ++m)
                    af[m] = *(const bhalf8*)(wt + (tap * 64 + m * 16 + l15) * 40 + l4 * 8);
#pragma unroll
                for (int n = 0; n < 4; ++n)
                    bf[n] = *(const bhalf8*)(xs + ((wv + dy) * 66 + n * 16 + l15 + dx) * 40 + l4 * 8);
#pragma unroll
                for (int m = 0; m < 4; ++m)
#pragma unroll
                    for (int n = 0; n < 4; ++n)
                        acc[m][n] = __builtin_amdgcn_mfma_f32_16x16x32_bf16(af[m], bf[n], acc[m][n], 0, 0, 0);
            }
        }
    }
    // ---- epilogue: demodulate + store (C/D: col=lane&15, row=(lane>>4)*4+reg)
    const int orow = r0 + wv;
#pragma unroll
    for (int m = 0; m < 4; ++m) {
#pragma unroll
        for (int r = 0; r < 4; ++r) {
            int cout = cout0 + m * 16 + l4 * 4 + r;
            float sg = sig[b * 512 + cout];
            float* op = out + (((size_t)b * 512 + cout) * 64 + orow) * 64;
#pragma unroll
            for (int n = 0; n < 4; ++n)
                op[n * 16 + l15] = acc[m][n][r] * sg;
        }
    }
}

// ---------------- launch ----------------------------------------------------
extern "C" void kernel_launch(void* const* d_in, const int* in_sizes, int n_in,
                              void* d_out, int out_size, void* d_ws, size_t ws_size,
                              hipStream_t stream) {
    const float* x  = (const float*)d_in[0];
    const float* s  = (const float*)d_in[1];
    const float* w0 = (const float*)d_in[2];
    const float* b0 = (const float*)d_in[3];
    const float* a0 = (const float*)d_in[4];
    const float* w1 = (const float*)d_in[5];
    const float* b1 = (const float*)d_in[6];
    const float* a1 = (const float*)d_in[7];
    const float* sw = (const float*)d_in[8];
    const float* sb = (const float*)d_in[9];
    const float* cw = (const float*)d_in[10];
    float* out = (float*)d_out;

    // workspace layout
    float*    style_c = (float*)d_ws;                       //  8192 f32
    float*    sig     = style_c + 8192;                     //  8192 f32
    float*    wsq     = sig + 8192;                         //  262144 f32
    ushort_t* wbf     = (ushort_t*)(wsq + 262144);          //  2359296 bf16 @ byte 1114112
    ushort_t* xm      = (ushort_t*)((char*)d_ws + 5832704); //  33554432 bf16 (67.1 MB)
    const bool xpre = ws_size >= 72941568ull;               //  5.83MB + 67.1MB

    style_k<<<16, 512, 0, stream>>>(s, w0, b0, a0, w1, b1, a1, sw, sb, style_c);
    wsq_k<<<1024, 256, 0, stream>>>(cw, wsq);
    sigma_k<<<16, 512, 0, stream>>>(style_c, wsq, sig);
    wbf_k<<<9216, 256, 0, stream>>>(cw, wbf);
    if (xpre) {
        xmod_k<<<dim3(64, 16), 256, 0, stream>>>(x, style_c, xm);
        conv_k<true><<<dim3(16, 8, 16), 256, 0, stream>>>(x, xm, wbf, style_c, sig, out);
    } else {
        conv_k<false><<<dim3(16, 8, 16), 256, 0, stream>>>(x, xm, wbf, style_c, sig, out);
    }
}

// Round 3
// 371.314 us; speedup vs baseline: 1.5826x; 1.5826x over previous
//
#include <hip/hip_runtime.h>

typedef unsigned short ushort_t;
typedef unsigned int uint_t;
typedef __attribute__((ext_vector_type(8))) short bhalf8;   // 8 bf16 (4 VGPRs)
typedef __attribute__((ext_vector_type(4))) float f32x4;

#define C_LIN  0.04419417382415922f     // 1/sqrt(512)
#define C_CONV 0.014731391274719738f    // 1/sqrt(512*9)

__device__ __forceinline__ ushort_t f2bf(float f) {
    uint_t u = __float_as_uint(f);
    u += 0x7fffu + ((u >> 16) & 1u);    // round-to-nearest-even
    return (ushort_t)(u >> 16);
}

__device__ __forceinline__ void gload16(const void* g, void* l) {
    __builtin_amdgcn_global_load_lds((const __attribute__((address_space(1))) void*)g,
                                     (__attribute__((address_space(3))) void*)l, 16, 0, 0);
}

// ---------------- mapping-network layer: zout = act(zin @ (w*C_LIN)^T + b) --
// grid (8, B), block 256: 64 outputs/block, 4 threads per output.
__global__ void map_layer_k(const float* __restrict__ zin, const float* __restrict__ w,
                            const float* __restrict__ bias, const float* __restrict__ alpha,
                            float* __restrict__ zout, int final_) {
    __shared__ float zs[512];
    const int b = blockIdx.y, tid = threadIdx.x;
    if (tid < 128) ((float4*)zs)[tid] = ((const float4*)(zin + b * 512))[tid];
    __syncthreads();
    const int j = blockIdx.x * 64 + (tid >> 2);
    const int part = (tid & 3) * 128;
    const float4* wr = (const float4*)(w + (size_t)j * 512 + part);
    const float* zp = zs + part;
    float acc = 0.f;
#pragma unroll 8
    for (int i = 0; i < 32; ++i) {
        float4 w4 = wr[i];
        acc += w4.x * zp[4*i] + w4.y * zp[4*i+1] + w4.z * zp[4*i+2] + w4.w * zp[4*i+3];
    }
    acc += __shfl_xor(acc, 1);
    acc += __shfl_xor(acc, 2);
    if ((tid & 3) == 0) {
        acc = acc * C_LIN + bias[j];
        if (final_) acc *= C_CONV;                       // fold c_conv into style
        else        acc = acc >= 0.f ? acc : alpha[j] * acc;
        zout[b * 512 + j] = acc;
    }
}

// ---------------- wsq[cout][cin] = sum_tap conv_w^2 -------------------------
__global__ void wsq_k(const float* __restrict__ cw, float* __restrict__ wsq) {
    int idx = blockIdx.x * 256 + threadIdx.x;   // < 262144
    const float* p = cw + (size_t)idx * 9;
    float sum = 0.f;
#pragma unroll
    for (int k = 0; k < 9; ++k) { float v = p[k]; sum += v * v; }
    wsq[idx] = sum;
}

// ---------------- sigma_inv[b][cout] ----------------------------------------
__global__ void sigma_k(const float* __restrict__ style_c, const float* __restrict__ wsq,
                        float* __restrict__ sig) {
    __shared__ float s2[512];
    const int b = blockIdx.x, c = threadIdx.x;
    float v = style_c[b * 512 + c];
    s2[c] = v * v;
    __syncthreads();
    const float4* wr = (const float4*)(wsq + (size_t)c * 512);
    float acc = 0.f;
    for (int i = 0; i < 128; ++i) {
        float4 w = wr[i];
        acc += w.x * s2[4*i] + w.y * s2[4*i+1] + w.z * s2[4*i+2] + w.w * s2[4*i+3];
    }
    sig[b * 512 + c] = 1.0f / sqrtf(acc + 1e-8f);
}

// ---------------- conv_w [co][ci][9] -> bf16 [tap][co][ci] ------------------
__global__ void wbf_k(const float* __restrict__ cw, ushort_t* __restrict__ wbf) {
    int idx = blockIdx.x * 256 + threadIdx.x;   // < 2359296
    int tap = idx >> 18;
    int rem = idx & 262143;
    int cout = rem >> 9, cin = rem & 511;
    wbf[idx] = f2bf(cw[(((size_t)cout * 512) + cin) * 9 + tap]);
}

// ---------------- x -> bf16 NHWC, style-modulated ---------------------------
__global__ void xmod_k(const float* __restrict__ x, const float* __restrict__ style_c,
                       ushort_t* __restrict__ xm) {
    const int y = blockIdx.x, b = blockIdx.y, tid = threadIdx.x;
    const float* xp = x + ((size_t)b * 512) * 4096 + y * 64;            // x[b][ci][y][0]
    ushort_t* op = xm + (((size_t)b * 64 + y) * 64) * 512;              // xm[b][y][x][ci]
    __shared__ ushort_t tile[32][65];
    for (int cin0 = 0; cin0 < 512; cin0 += 32) {
        for (int i = tid; i < 2048; i += 256) {                         // (ci, x) load, coalesced
            int ci = i >> 6, xc = i & 63;
            float v = xp[(size_t)(cin0 + ci) * 4096 + xc] * style_c[b * 512 + cin0 + ci];
            tile[ci][xc] = f2bf(v);
        }
        __syncthreads();
        for (int i = tid; i < 2048; i += 256) {                         // (x, ci) store, ci fastest
            int xc = i >> 5, ci = i & 31;
            op[(size_t)xc * 512 + cin0 + ci] = tile[ci][xc];
        }
        __syncthreads();
    }
}

// ---------------- implicit-GEMM conv via MFMA -------------------------------
// Block: 64 couts x (8 rows x 64 cols). 4 waves, each 64 couts x 2 rows.
// LDS sigma-swizzle on 16B blocks within 32-block windows:
//   physical (k=bits[4:3], s=bits[2:0]) holds logical (pos = s^2k, group k).
// X: 660 logical positions (10 rows x 66 cols) x 4 groups = 2640 blocks, padded
// to 42 slots x 64 blocks = 2688. Slot u handled by wave u&3 (u = wv + 4t).
template <bool XPRE>
__global__ __launch_bounds__(256, 2)
void conv_k(const float* __restrict__ x, const ushort_t* __restrict__ xm,
            const ushort_t* __restrict__ wbf, const float* __restrict__ style_c,
            const float* __restrict__ sig, float* __restrict__ out) {
    __shared__ __align__(16) ushort_t wt[18432];   // 36864 B: 9 taps x 64 co x 32 ci
    __shared__ __align__(16) ushort_t xs[21504];   // 43008 B: 2688 16B-blocks

    const int tid  = threadIdx.x;
    const int lane = tid & 63;
    const int wv   = tid >> 6;
    const int l15  = lane & 15, l4 = lane >> 4;

    // XCD-aware bijective block swizzle (nwg=1024, 8 XCDs): batch-major chunks.
    const int bid = blockIdx.x;
    const int swz = (bid & 7) * 128 + (bid >> 3);
    const int b     = swz >> 6;
    const int cout0 = ((swz >> 3) & 7) * 64;
    const int r0    = (swz & 7) * 8;

    const int nx = (wv < 2) ? 11 : 10;             // X slots per wave (42 total)

    // ---- per-thread staging source offsets (element units, +c0 per chunk)
    int gw[9];
#pragma unroll
    for (int t = 0; t < 9; ++t) {
        int L = (wv * 9 + t) * 64 + lane;          // physical 16B-block in wt
        int tap = L >> 8, win = (L >> 5) & 7, k = (L >> 3) & 3, s = L & 7;
        int c = win * 8 + ((s ^ (k * 2)) & 7);     // logical cout_local
        gw[t] = ((tap * 512 + cout0 + c) << 9) + k * 8;
    }
    int gxo[11];
#pragma unroll
    for (int t = 0; t < 11; ++t) {
        if (t < nx) {
            int L = (wv + 4 * t) * 64 + lane;      // physical block in xs, slot u=wv+4t
            int k = (L >> 3) & 3, s = L & 7;
            int p = ((L >> 5) << 3) | ((s ^ (k * 2)) & 7);
            p = min(p, 659);                        // pad-region lanes: safe duplicate
            int row = p / 66, col = p - row * 66;
            int gy = min(max(r0 - 1 + row, 0), 63);
            int gx = min(max(col - 1, 0), 63);
            gxo[t] = (((b * 64 + gy) * 64 + gx) << 9) + k * 8;   // xm element offset
        } else gxo[t] = 0;
    }

    f32x4 acc[2][4][4] = {};
    const int base_af = (l15 >> 3) * 512 + l4 * 128 + (((l15 & 7) ^ (l4 * 2)) & 7) * 16;

    for (int c0 = 0; c0 < 512; c0 += 32) {
        __syncthreads();                            // prev chunk's readers done
        // ---- stage W (linear LDS dest, pre-swizzled global source)
#pragma unroll
        for (int t = 0; t < 9; ++t)
            gload16(wbf + gw[t] + c0, (char*)wt + (wv * 9 + t) * 1024);
        // ---- stage X
        if (XPRE) {
#pragma unroll
            for (int t = 0; t < 11; ++t)
                if (t < nx)
                    gload16(xm + gxo[t] + c0, (char*)xs + (wv + 4 * t) * 1024);
        } else {
#pragma unroll
            for (int t = 0; t < 11; ++t) {
                if (t < nx) {
                    int L = (wv + 4 * t) * 64 + lane;
                    int k = (L >> 3) & 3, s = L & 7;
                    int p = ((L >> 5) << 3) | ((s ^ (k * 2)) & 7);
                    p = min(p, 659);
                    int row = p / 66, col = p - row * 66;
                    int gy = min(max(r0 - 1 + row, 0), 63);
                    int gx = min(max(col - 1, 0), 63);
                    const float* xp = x + ((size_t)(b * 512 + c0 + k * 8)) * 4096 + gy * 64 + gx;
                    const float* sc = style_c + b * 512 + c0 + k * 8;
                    ushort_t tmp[8];
#pragma unroll
                    for (int e = 0; e < 8; ++e)
                        tmp[e] = f2bf(xp[(size_t)e * 4096] * sc[e]);
                    *(bhalf8*)((char*)xs + (size_t)L * 16) = *(const bhalf8*)tmp;
                }
            }
        }
        asm volatile("s_waitcnt vmcnt(0)" ::: "memory");
        __syncthreads();

        // ---- compute: dx-major, af held for all dy, bf per input row
#pragma unroll
        for (int dx = 0; dx < 3; ++dx) {
            bhalf8 af[3][4];
#pragma unroll
            for (int dy = 0; dy < 3; ++dy)
#pragma unroll
                for (int m = 0; m < 4; ++m)
                    af[dy][m] = *(const bhalf8*)((const char*)wt + base_af + (dy * 3 + dx) * 4096 + m * 1024);
#pragma unroll
            for (int ri = 0; ri < 4; ++ri) {
                const int p0 = (wv * 2 + ri) * 66 + dx + l15;
                const int bb = (p0 >> 3) * 512 + l4 * 128 + (((p0 & 7) ^ (l4 * 2)) & 7) * 16;
                bhalf8 bfr[4];
#pragma unroll
                for (int n = 0; n < 4; ++n)
                    bfr[n] = *(const bhalf8*)((const char*)xs + bb + n * 1024);
#pragma unroll
                for (int dy = 0; dy < 3; ++dy) {
                    const int r_out = ri - dy;
                    if (r_out < 0 || r_out > 1) continue;
#pragma unroll
                    for (int m = 0; m < 4; ++m)
#pragma unroll
                        for (int n = 0; n < 4; ++n)
                            acc[r_out][m][n] = __builtin_amdgcn_mfma_f32_16x16x32_bf16(
                                af[dy][m], bfr[n], acc[r_out][m][n], 0, 0, 0);
                }
            }
        }
    }

    // ---- epilogue: demodulate + store (C/D: col=lane&15, row=(lane>>4)*4+reg)
#pragma unroll
    for (int r_out = 0; r_out < 2; ++r_out) {
        const int orow = r0 + wv * 2 + r_out;
#pragma unroll
        for (int m = 0; m < 4; ++m) {
#pragma unroll
            for (int r = 0; r < 4; ++r) {
                int cout = cout0 + m * 16 + l4 * 4 + r;
                float sg = sig[b * 512 + cout];
                float* op = out + (((size_t)b * 512 + cout) * 64 + orow) * 64;
#pragma unroll
                for (int n = 0; n < 4; ++n)
                    op[n * 16 + l15] = acc[r_out][m][n][r] * sg;
            }
        }
    }
}

// ---------------- launch ----------------------------------------------------
extern "C" void kernel_launch(void* const* d_in, const int* in_sizes, int n_in,
                              void* d_out, int out_size, void* d_ws, size_t ws_size,
                              hipStream_t stream) {
    const float* x  = (const float*)d_in[0];
    const float* s  = (const float*)d_in[1];
    const float* w0 = (const float*)d_in[2];
    const float* b0 = (const float*)d_in[3];
    const float* a0 = (const float*)d_in[4];
    const float* w1 = (const float*)d_in[5];
    const float* b1 = (const float*)d_in[6];
    const float* a1 = (const float*)d_in[7];
    const float* sw = (const float*)d_in[8];
    const float* sb = (const float*)d_in[9];
    const float* cw = (const float*)d_in[10];
    float* out = (float*)d_out;

    // workspace layout (f32 elements unless noted)
    float*    style_c = (float*)d_ws;                       // 8192
    float*    sig     = style_c + 8192;                     // 8192
    float*    zt0     = sig + 8192;                         // 8192
    float*    zt1     = zt0 + 8192;                         // 8192
    float*    wsq     = zt1 + 8192;                         // 262144
    ushort_t* wbf     = (ushort_t*)(wsq + 262144);          // 2359296 bf16
    ushort_t* xm      = (ushort_t*)((char*)d_ws + 5898240); // 33554432 bf16 (67.1 MB)
    const bool xpre = ws_size >= 73007104ull;

    map_layer_k<<<dim3(8, 16), 256, 0, stream>>>(s,   w0, b0, a0, zt0,     0);
    map_layer_k<<<dim3(8, 16), 256, 0, stream>>>(zt0, w1, b1, a1, zt1,     0);
    map_layer_k<<<dim3(8, 16), 256, 0, stream>>>(zt1, sw, sb, a1, style_c, 1);
    wsq_k<<<1024, 256, 0, stream>>>(cw, wsq);
    sigma_k<<<16, 512, 0, stream>>>(style_c, wsq, sig);
    wbf_k<<<9216, 256, 0, stream>>>(cw, wbf);
    if (xpre) {
        xmod_k<<<dim3(64, 16), 256, 0, stream>>>(x, style_c, xm);
        conv_k<true><<<1024, 256, 0, stream>>>(x, xm, wbf, style_c, sig, out);
    } else {
        conv_k<false><<<1024, 256, 0, stream>>>(x, xm, wbf, style_c, sig, out);
    }
}